// Round 1
// baseline (346.375 us; speedup 1.0000x reference)
//
#include <hip/hip_runtime.h>
#include <hip/hip_bf16.h>

#define NUM_HEADS 16
#define HEAD_DIM 64
#define DMODEL 1024
#define SEQ 2048
#define BATCH 2
#define MROWS (BATCH*SEQ)

typedef __bf16 bf16;
typedef __bf16 bf16x4 __attribute__((ext_vector_type(4)));
typedef __bf16 bf16x8 __attribute__((ext_vector_type(8)));
typedef float f32x4 __attribute__((ext_vector_type(4)));

#define MFMA16(a, b, c) __builtin_amdgcn_mfma_f32_16x16x32_bf16((a), (b), (c), 0, 0, 0)

__device__ __forceinline__ void gld16(const void* g, void* l) {
    __builtin_amdgcn_global_load_lds(
        (const __attribute__((address_space(1))) void*)g,
        (__attribute__((address_space(3))) void*)l, 16, 0, 0);
}

// ---------------- conversion kernels ----------------

__global__ __launch_bounds__(256) void cvt_f32_bf16(const float* __restrict__ in,
                                                    bf16* __restrict__ out, int n4) {
    int i = blockIdx.x * 256 + threadIdx.x;
    if (i >= n4) return;
    float4 v = *(const float4*)(in + (size_t)i * 4);
    bf16x4 o = { (bf16)v.x, (bf16)v.y, (bf16)v.z, (bf16)v.w };
    *(bf16x4*)(out + (size_t)i * 4) = o;
}

// w [1024][1024] f32 -> wT bf16 [1024][1024], wT[n][k] = w[k][n]
__global__ __launch_bounds__(256) void cvt_trans(const float* __restrict__ w0, const float* __restrict__ w1,
                                                 const float* __restrict__ w2, const float* __restrict__ w3,
                                                 bf16* __restrict__ o0, bf16* __restrict__ o1,
                                                 bf16* __restrict__ o2, bf16* __restrict__ o3) {
    const float* w = blockIdx.z == 0 ? w0 : blockIdx.z == 1 ? w1 : blockIdx.z == 2 ? w2 : w3;
    bf16* o = blockIdx.z == 0 ? o0 : blockIdx.z == 1 ? o1 : blockIdx.z == 2 ? o2 : o3;
    __shared__ bf16 tile[64][65];
    int k0 = blockIdx.y * 64, n0 = blockIdx.x * 64;
    int tc = threadIdx.x & 63;
    int tr0 = threadIdx.x >> 6;
#pragma unroll
    for (int i = 0; i < 16; i++) {
        int r = tr0 + i * 4;  // k row
        tile[r][tc] = (bf16)w[(size_t)(k0 + r) * DMODEL + n0 + tc];
    }
    __syncthreads();
#pragma unroll
    for (int i = 0; i < 16; i++) {
        int r = tr0 + i * 4;  // n row of output
        o[(size_t)(n0 + r) * DMODEL + k0 + tc] = tile[tc][r];
    }
}

// ---------------- GEMM core: C[128][128] tile = A[m][k] * Bt[n][k]^T ----------------

#define BM 128
#define BN 128
#define BK 32

__device__ __forceinline__ void gemm_core(const bf16* __restrict__ A, const bf16* __restrict__ Bt,
                                          int m0, int n0, int Kdim,
                                          bf16* As, bf16* Bs, f32x4 acc[4][4]) {
    int t = threadIdx.x;
    int lane = t & 63;
    int wave = t >> 6;
    int wm = (wave >> 1) * 64;
    int wn = (wave & 1) * 64;
#pragma unroll
    for (int mf = 0; mf < 4; mf++)
#pragma unroll
        for (int nf = 0; nf < 4; nf++) acc[mf][nf] = (f32x4){0.f, 0.f, 0.f, 0.f};

    int arow = lane & 15, kg = lane >> 4;

    for (int k0 = 0; k0 < Kdim; k0 += BK) {
        __syncthreads();
#pragma unroll
        for (int it = 0; it < 2; it++) {
            int chunk = it * 256 + t;
            int rr = chunk >> 2, cc = chunk & 3;
            gld16(A + (size_t)(m0 + rr) * Kdim + k0 + cc * 8, As + chunk * 8);
            gld16(Bt + (size_t)(n0 + rr) * Kdim + k0 + cc * 8, Bs + chunk * 8);
        }
        __syncthreads();
        bf16x8 af[4], bfr[4];
#pragma unroll
        for (int mf = 0; mf < 4; mf++)
            af[mf] = *(const bf16x8*)(As + (wm + mf * 16 + arow) * BK + kg * 8);
#pragma unroll
        for (int nf = 0; nf < 4; nf++)
            bfr[nf] = *(const bf16x8*)(Bs + (wn + nf * 16 + arow) * BK + kg * 8);
#pragma unroll
        for (int mf = 0; mf < 4; mf++)
#pragma unroll
            for (int nf = 0; nf < 4; nf++)
                acc[mf][nf] = MFMA16(af[mf], bfr[nf], acc[mf][nf]);
    }
}

// z=0 -> Q linear bf16 [4096][1024]; z=1 -> K linear; z=2 -> V transposed [B][H][D][S]
__global__ __launch_bounds__(256) void gemm_qkv(const bf16* __restrict__ xb,
                                                const bf16* __restrict__ wqT, const bf16* __restrict__ wkT,
                                                const bf16* __restrict__ wvT,
                                                bf16* __restrict__ Qm, bf16* __restrict__ Km,
                                                bf16* __restrict__ Vt) {
    __shared__ __attribute__((aligned(16))) bf16 As[BM * BK];
    __shared__ __attribute__((aligned(16))) bf16 Bs[BN * BK];
    int z = blockIdx.z;
    const bf16* Bt = z == 0 ? wqT : z == 1 ? wkT : wvT;
    int m0 = blockIdx.y * BM, n0 = blockIdx.x * BN;
    f32x4 acc[4][4];
    gemm_core(xb, Bt, m0, n0, DMODEL, As, Bs, acc);

    int lane = threadIdx.x & 63, wave = threadIdx.x >> 6;
    int wm = (wave >> 1) * 64, wn = (wave & 1) * 64;
    int col0 = n0 + wn + (lane & 15);
    int row0 = m0 + wm + (lane >> 4) * 4;
    if (z < 2) {
        bf16* O = z == 0 ? Qm : Km;
#pragma unroll
        for (int mf = 0; mf < 4; mf++)
#pragma unroll
            for (int nf = 0; nf < 4; nf++) {
                int n = col0 + nf * 16;
                int mb = row0 + mf * 16;
#pragma unroll
                for (int i2 = 0; i2 < 4; i2++)
                    O[(size_t)(mb + i2) * DMODEL + n] = (bf16)acc[mf][nf][i2];
            }
    } else {
#pragma unroll
        for (int mf = 0; mf < 4; mf++)
#pragma unroll
            for (int nf = 0; nf < 4; nf++) {
                int n = col0 + nf * 16;
                int m = row0 + mf * 16;
                int b = m >> 11, s = m & 2047;
                int h = n >> 6, d = n & 63;
                bf16x4 pack = { (bf16)acc[mf][nf][0], (bf16)acc[mf][nf][1],
                                (bf16)acc[mf][nf][2], (bf16)acc[mf][nf][3] };
                *(bf16x4*)(Vt + ((size_t)(b * NUM_HEADS + h) * HEAD_DIM + d) * SEQ + s) = pack;
            }
    }
}

__global__ __launch_bounds__(256) void gemm_outp(const bf16* __restrict__ at,
                                                 const bf16* __restrict__ woT,
                                                 float* __restrict__ out) {
    __shared__ __attribute__((aligned(16))) bf16 As[BM * BK];
    __shared__ __attribute__((aligned(16))) bf16 Bs[BN * BK];
    int m0 = blockIdx.y * BM, n0 = blockIdx.x * BN;
    f32x4 acc[4][4];
    gemm_core(at, woT, m0, n0, DMODEL, As, Bs, acc);

    int lane = threadIdx.x & 63, wave = threadIdx.x >> 6;
    int wm = (wave >> 1) * 64, wn = (wave & 1) * 64;
    int col0 = n0 + wn + (lane & 15);
    int row0 = m0 + wm + (lane >> 4) * 4;
#pragma unroll
    for (int mf = 0; mf < 4; mf++)
#pragma unroll
        for (int nf = 0; nf < 4; nf++) {
            int n = col0 + nf * 16;
            int mb = row0 + mf * 16;
#pragma unroll
            for (int i2 = 0; i2 < 4; i2++)
                out[(size_t)(mb + i2) * DMODEL + n] = acc[mf][nf][i2];
        }
}

// ---------------- flash attention ----------------
// grid (32, 16, 2), block 256. 4 waves x 16 q rows. KVBLK=64.
__global__ __launch_bounds__(256) void attn_kernel(const bf16* __restrict__ Q, const bf16* __restrict__ K,
                                                   const bf16* __restrict__ Vt, bf16* __restrict__ attn) {
    __shared__ __attribute__((aligned(16))) bf16 Pl[4 * 16 * 64];
    int qb = blockIdx.x;
    int h = blockIdx.y;
    int b = blockIdx.z;
    int t = threadIdx.x, lane = t & 63, wave = t >> 6;
    int l15 = lane & 15, lg = lane >> 4;

    const bf16* Qb = Q + ((size_t)(b * SEQ) * NUM_HEADS + h) * HEAD_DIM;
    const bf16* Kb = K + ((size_t)(b * SEQ) * NUM_HEADS + h) * HEAD_DIM;
    const bf16* Vb = Vt + ((size_t)(b * NUM_HEADS + h) * HEAD_DIM) * SEQ;

    int q0 = qb * 64 + wave * 16;

    bf16x8 aq[2];
#pragma unroll
    for (int ks = 0; ks < 2; ks++)
        aq[ks] = *(const bf16x8*)(Qb + (size_t)(q0 + l15) * DMODEL + ks * 32 + lg * 8);

    f32x4 oacc[4];
#pragma unroll
    for (int df = 0; df < 4; df++) oacc[df] = (f32x4){0.f, 0.f, 0.f, 0.f};
    float mrun[4], lrun[4];
#pragma unroll
    for (int i = 0; i < 4; i++) { mrun[i] = -1e30f; lrun[i] = 0.f; }

    bf16* Pw = Pl + wave * 16 * 64;
    const float scale = 0.125f;

    int nkt = qb + 1;
    for (int kt = 0; kt < nkt; kt++) {
        int kv0 = kt * 64;
        f32x4 s[4];
#pragma unroll
        for (int cf = 0; cf < 4; cf++) {
            s[cf] = (f32x4){0.f, 0.f, 0.f, 0.f};
#pragma unroll
            for (int ks = 0; ks < 2; ks++) {
                bf16x8 bk = *(const bf16x8*)(Kb + (size_t)(kv0 + cf * 16 + l15) * DMODEL + ks * 32 + lg * 8);
                s[cf] = MFMA16(aq[ks], bk, s[cf]);
            }
        }
        float z[4][4];
        bool diag = (kt == qb);
#pragma unroll
        for (int cf = 0; cf < 4; cf++) {
            int kvcol = kv0 + cf * 16 + l15;
#pragma unroll
            for (int i = 0; i < 4; i++) {
                int qrow = q0 + lg * 4 + i;
                float v = s[cf][i] * scale;
                if (diag && kvcol > qrow) v = -1e30f;
                z[cf][i] = v;
            }
        }
#pragma unroll
        for (int i = 0; i < 4; i++) {
            float mx = fmaxf(fmaxf(z[0][i], z[1][i]), fmaxf(z[2][i], z[3][i]));
#pragma unroll
            for (int off = 1; off < 16; off <<= 1)
                mx = fmaxf(mx, __shfl_xor(mx, off, 64));
            float mnew = fmaxf(mrun[i], mx);
            float alpha = __expf(mrun[i] - mnew);
            float ps = 0.f;
#pragma unroll
            for (int cf = 0; cf < 4; cf++) {
                float p = __expf(z[cf][i] - mnew);
                z[cf][i] = p;
                ps += p;
            }
#pragma unroll
            for (int off = 1; off < 16; off <<= 1)
                ps += __shfl_xor(ps, off, 64);
            lrun[i] = lrun[i] * alpha + ps;
            mrun[i] = mnew;
#pragma unroll
            for (int df = 0; df < 4; df++) oacc[df][i] *= alpha;
        }
        // write P to per-wave LDS tile, XOR-swizzled 16B slots
#pragma unroll
        for (int cf = 0; cf < 4; cf++) {
#pragma unroll
            for (int i = 0; i < 4; i++) {
                int rrow = lg * 4 + i;
                int ccol = cf * 16 + l15;
                int off = rrow * 128 + ccol * 2;
                off ^= ((rrow & 7) << 4);
                *(bf16*)((char*)Pw + off) = (bf16)z[cf][i];
            }
        }
        asm volatile("s_waitcnt lgkmcnt(0)" ::: "memory");
        // PV: O += P[16][64] * V[64][64]
#pragma unroll
        for (int ks = 0; ks < 2; ks++) {
            int boff = l15 * 128 + ks * 64 + lg * 16;
            boff ^= ((l15 & 7) << 4);
            bf16x8 ap = *(const bf16x8*)((char*)Pw + boff);
#pragma unroll
            for (int df = 0; df < 4; df++) {
                bf16x8 bv = *(const bf16x8*)(Vb + (size_t)(df * 16 + l15) * SEQ + kv0 + ks * 32 + lg * 8);
                oacc[df] = MFMA16(ap, bv, oacc[df]);
            }
        }
    }
    bf16* Ob = attn + ((size_t)(b * SEQ) * NUM_HEADS + h) * HEAD_DIM;
#pragma unroll
    for (int df = 0; df < 4; df++) {
#pragma unroll
        for (int i = 0; i < 4; i++) {
            int qrow = q0 + lg * 4 + i;
            int d = df * 16 + l15;
            Ob[(size_t)qrow * DMODEL + d] = (bf16)(oacc[df][i] / lrun[i]);
        }
    }
}

// ---------------- launch ----------------

extern "C" void kernel_launch(void* const* d_in, const int* in_sizes, int n_in,
                              void* d_out, int out_size, void* d_ws, size_t ws_size,
                              hipStream_t stream) {
    const float* x  = (const float*)d_in[0];
    const float* wq = (const float*)d_in[1];
    const float* wk = (const float*)d_in[2];
    const float* wv = (const float*)d_in[3];
    const float* wo = (const float*)d_in[4];
    float* out = (float*)d_out;

    char* w = (char*)d_ws;
    bf16* xb  = (bf16*)(w);                        // 8 MB
    bf16* wqT = (bf16*)(w + (8ull  << 20));        // 2 MB
    bf16* wkT = (bf16*)(w + (10ull << 20));
    bf16* wvT = (bf16*)(w + (12ull << 20));
    bf16* woT = (bf16*)(w + (14ull << 20));
    bf16* Qm  = (bf16*)(w + (16ull << 20));        // 8 MB
    bf16* Km  = (bf16*)(w + (24ull << 20));        // 8 MB
    bf16* Vt  = (bf16*)(w + (32ull << 20));        // 8 MB
    bf16* at  = (bf16*)(w + (40ull << 20));        // 8 MB  (total 48 MB)

    cvt_f32_bf16<<<(MROWS * DMODEL / 4 + 255) / 256, 256, 0, stream>>>(x, xb, MROWS * DMODEL / 4);
    cvt_trans<<<dim3(16, 16, 4), 256, 0, stream>>>(wq, wk, wv, wo, wqT, wkT, wvT, woT);
    gemm_qkv<<<dim3(DMODEL / BN, MROWS / BM, 3), 256, 0, stream>>>(xb, wqT, wkT, wvT, Qm, Km, Vt);
    attn_kernel<<<dim3(SEQ / 64, NUM_HEADS, BATCH), 256, 0, stream>>>(Qm, Km, Vt, at);
    gemm_outp<<<dim3(DMODEL / BN, MROWS / BM), 256, 0, stream>>>(at, woT, out);
}

// Round 2
// 210.385 us; speedup vs baseline: 1.6464x; 1.6464x over previous
//
#include <hip/hip_runtime.h>
#include <hip/hip_bf16.h>

#define NUM_HEADS 16
#define HEAD_DIM 64
#define DMODEL 1024
#define SEQ 2048
#define BATCH 2
#define MROWS (BATCH*SEQ)

typedef __bf16 bf16;
typedef __bf16 bf16x4 __attribute__((ext_vector_type(4)));
typedef __bf16 bf16x8 __attribute__((ext_vector_type(8)));
typedef float f32x4 __attribute__((ext_vector_type(4)));

#define MFMA16(a, b, c) __builtin_amdgcn_mfma_f32_16x16x32_bf16((a), (b), (c), 0, 0, 0)

// 0.125 * log2(e): folded into Q so QK^T logits land in exp2 domain
#define QSCALE 0.1803368801111444f

__device__ __forceinline__ void gld16(const void* g, void* l) {
    __builtin_amdgcn_global_load_lds(
        (const __attribute__((address_space(1))) void*)g,
        (__attribute__((address_space(3))) void*)l, 16, 0, 0);
}

// ---------------- conversion kernels ----------------

__global__ __launch_bounds__(256) void cvt_f32_bf16(const float* __restrict__ in,
                                                    bf16* __restrict__ out, int n4) {
    int i = blockIdx.x * 256 + threadIdx.x;
    if (i >= n4) return;
    float4 v = *(const float4*)(in + (size_t)i * 4);
    bf16x4 o = { (bf16)v.x, (bf16)v.y, (bf16)v.z, (bf16)v.w };
    *(bf16x4*)(out + (size_t)i * 4) = o;
}

// w [1024][1024] f32 -> wT bf16 [1024][1024], wT[n][k] = w[k][n]
__global__ __launch_bounds__(256) void cvt_trans(const float* __restrict__ w0, const float* __restrict__ w1,
                                                 const float* __restrict__ w2, const float* __restrict__ w3,
                                                 bf16* __restrict__ o0, bf16* __restrict__ o1,
                                                 bf16* __restrict__ o2, bf16* __restrict__ o3) {
    const float* w = blockIdx.z == 0 ? w0 : blockIdx.z == 1 ? w1 : blockIdx.z == 2 ? w2 : w3;
    bf16* o = blockIdx.z == 0 ? o0 : blockIdx.z == 1 ? o1 : blockIdx.z == 2 ? o2 : o3;
    __shared__ bf16 tile[64][65];
    int k0 = blockIdx.y * 64, n0 = blockIdx.x * 64;
    int tc = threadIdx.x & 63;
    int tr0 = threadIdx.x >> 6;
#pragma unroll
    for (int i = 0; i < 16; i++) {
        int r = tr0 + i * 4;  // k row
        tile[r][tc] = (bf16)w[(size_t)(k0 + r) * DMODEL + n0 + tc];
    }
    __syncthreads();
#pragma unroll
    for (int i = 0; i < 16; i++) {
        int r = tr0 + i * 4;  // n row of output
        o[(size_t)(n0 + r) * DMODEL + k0 + tc] = tile[tc][r];
    }
}

// ---------------- GEMM core: C[128][128] tile = A[m][k] * Bt[n][k]^T ----------------

#define BM 128
#define BN 128
#define BK 32

__device__ __forceinline__ void gemm_core(const bf16* __restrict__ A, const bf16* __restrict__ Bt,
                                          int m0, int n0, int Kdim,
                                          bf16* As, bf16* Bs, f32x4 acc[4][4]) {
    int t = threadIdx.x;
    int lane = t & 63;
    int wave = t >> 6;
    int wm = (wave >> 1) * 64;
    int wn = (wave & 1) * 64;
#pragma unroll
    for (int mf = 0; mf < 4; mf++)
#pragma unroll
        for (int nf = 0; nf < 4; nf++) acc[mf][nf] = (f32x4){0.f, 0.f, 0.f, 0.f};

    int arow = lane & 15, kg = lane >> 4;

    for (int k0 = 0; k0 < Kdim; k0 += BK) {
        __syncthreads();
#pragma unroll
        for (int it = 0; it < 2; it++) {
            int chunk = it * 256 + t;
            int rr = chunk >> 2, cc = chunk & 3;
            gld16(A + (size_t)(m0 + rr) * Kdim + k0 + cc * 8, As + chunk * 8);
            gld16(Bt + (size_t)(n0 + rr) * Kdim + k0 + cc * 8, Bs + chunk * 8);
        }
        __syncthreads();
        bf16x8 af[4], bfr[4];
#pragma unroll
        for (int mf = 0; mf < 4; mf++)
            af[mf] = *(const bf16x8*)(As + (wm + mf * 16 + arow) * BK + kg * 8);
#pragma unroll
        for (int nf = 0; nf < 4; nf++)
            bfr[nf] = *(const bf16x8*)(Bs + (wn + nf * 16 + arow) * BK + kg * 8);
#pragma unroll
        for (int mf = 0; mf < 4; mf++)
#pragma unroll
            for (int nf = 0; nf < 4; nf++)
                acc[mf][nf] = MFMA16(af[mf], bfr[nf], acc[mf][nf]);
    }
}

// z=0 -> Q head-major [B][H][S][D], pre-scaled by QSCALE; z=1 -> K head-major; z=2 -> V [B][H][D][S]
__global__ __launch_bounds__(256) void gemm_qkv(const bf16* __restrict__ xb,
                                                const bf16* __restrict__ wqT, const bf16* __restrict__ wkT,
                                                const bf16* __restrict__ wvT,
                                                bf16* __restrict__ Qh, bf16* __restrict__ Kh,
                                                bf16* __restrict__ Vt) {
    __shared__ __attribute__((aligned(16))) bf16 As[BM * BK];
    __shared__ __attribute__((aligned(16))) bf16 Bs[BN * BK];
    int z = blockIdx.z;
    const bf16* Bt = z == 0 ? wqT : z == 1 ? wkT : wvT;
    int m0 = blockIdx.y * BM, n0 = blockIdx.x * BN;
    f32x4 acc[4][4];
    gemm_core(xb, Bt, m0, n0, DMODEL, As, Bs, acc);

    int lane = threadIdx.x & 63, wave = threadIdx.x >> 6;
    int wm = (wave >> 1) * 64, wn = (wave & 1) * 64;
    int col0 = n0 + wn + (lane & 15);
    int row0 = m0 + wm + (lane >> 4) * 4;
    if (z < 2) {
        bf16* O = z == 0 ? Qh : Kh;
        float scl = z == 0 ? QSCALE : 1.0f;
#pragma unroll
        for (int mf = 0; mf < 4; mf++)
#pragma unroll
            for (int nf = 0; nf < 4; nf++) {
                int n = col0 + nf * 16;
                int mb = row0 + mf * 16;
                int hh = n >> 6, d = n & 63;
#pragma unroll
                for (int i2 = 0; i2 < 4; i2++) {
                    int m = mb + i2;
                    int bb = m >> 11, s = m & 2047;
                    O[(((size_t)bb * NUM_HEADS + hh) * SEQ + s) * HEAD_DIM + d] =
                        (bf16)(acc[mf][nf][i2] * scl);
                }
            }
    } else {
#pragma unroll
        for (int mf = 0; mf < 4; mf++)
#pragma unroll
            for (int nf = 0; nf < 4; nf++) {
                int n = col0 + nf * 16;
                int m = row0 + mf * 16;
                int b = m >> 11, s = m & 2047;
                int h = n >> 6, d = n & 63;
                bf16x4 pack = { (bf16)acc[mf][nf][0], (bf16)acc[mf][nf][1],
                                (bf16)acc[mf][nf][2], (bf16)acc[mf][nf][3] };
                *(bf16x4*)(Vt + ((size_t)(b * NUM_HEADS + h) * HEAD_DIM + d) * SEQ + s) = pack;
            }
    }
}

__global__ __launch_bounds__(256) void gemm_outp(const bf16* __restrict__ at,
                                                 const bf16* __restrict__ woT,
                                                 float* __restrict__ out) {
    __shared__ __attribute__((aligned(16))) bf16 As[BM * BK];
    __shared__ __attribute__((aligned(16))) bf16 Bs[BN * BK];
    int m0 = blockIdx.y * BM, n0 = blockIdx.x * BN;
    f32x4 acc[4][4];
    gemm_core(at, woT, m0, n0, DMODEL, As, Bs, acc);

    int lane = threadIdx.x & 63, wave = threadIdx.x >> 6;
    int wm = (wave >> 1) * 64, wn = (wave & 1) * 64;
    int col0 = n0 + wn + (lane & 15);
    int row0 = m0 + wm + (lane >> 4) * 4;
#pragma unroll
    for (int mf = 0; mf < 4; mf++)
#pragma unroll
        for (int nf = 0; nf < 4; nf++) {
            int n = col0 + nf * 16;
            int mb = row0 + mf * 16;
#pragma unroll
            for (int i2 = 0; i2 < 4; i2++)
                out[(size_t)(mb + i2) * DMODEL + n] = acc[mf][nf][i2];
        }
}

// ---------------- flash attention, swapped-QK^T ----------------
// grid 2048 x 1, block 128 (2 independent waves; each wave: 16 q rows, KVBLK=64).
// XCD remap: id&7 = xcd; each XCD handles 4 (b,h) pairs -> K+V 2MB, fits 4MB L2.
// Swapped QK^T: st = mfma(K_frag, Q_frag) => lane owns P[q=l15][kv: lg*4+i per cf].
__global__ __launch_bounds__(128) void attn_kernel(const bf16* __restrict__ Qh, const bf16* __restrict__ Kh,
                                                   const bf16* __restrict__ Vt, bf16* __restrict__ attn) {
    __shared__ __attribute__((aligned(16))) bf16 Pl[2 * 16 * 64];
    int id = blockIdx.x;
    int xcd = id & 7, j = id >> 3;
    int hb = xcd * 4 + (j & 3);
    int qp = j >> 2;
    int b = hb >> 4, h = hb & 15;
    int t = threadIdx.x, lane = t & 63, wave = t >> 6;
    int l15 = lane & 15, lg = lane >> 4;
    int q0 = (qp * 2 + wave) * 16;

    const bf16* Qb = Qh + ((size_t)(b * NUM_HEADS + h) * SEQ) * HEAD_DIM;
    const bf16* Kb = Kh + ((size_t)(b * NUM_HEADS + h) * SEQ) * HEAD_DIM;
    const bf16* Vb = Vt + ((size_t)(b * NUM_HEADS + h) * HEAD_DIM) * SEQ;  // [D][S]

    // Q fragment for q rows q0..q0+15 (pre-scaled by QSCALE in GEMM epilogue)
    bf16x8 qf[2];
#pragma unroll
    for (int ks = 0; ks < 2; ks++)
        qf[ks] = *(const bf16x8*)(Qb + (size_t)(q0 + l15) * HEAD_DIM + ks * 32 + lg * 8);

    f32x4 oacc[4];
#pragma unroll
    for (int df = 0; df < 4; df++) oacc[df] = (f32x4){0.f, 0.f, 0.f, 0.f};
    float mrun = -1e30f, lrun = 0.f;

    char* Pw = (char*)Pl + wave * 2048;
    int swz = (l15 & 7) << 4;

    int nkt = (q0 + 15) / 64 + 1;
    for (int kt = 0; kt < nkt; kt++) {
        int kv0 = kt * 64;
        // S^T fragments: st[cf][i] = S[q=q0+l15][kv = kv0 + cf*16 + lg*4 + i]
        f32x4 st[4];
#pragma unroll
        for (int cf = 0; cf < 4; cf++) {
            st[cf] = (f32x4){0.f, 0.f, 0.f, 0.f};
#pragma unroll
            for (int ks = 0; ks < 2; ks++) {
                bf16x8 kf = *(const bf16x8*)(Kb + (size_t)(kv0 + cf * 16 + l15) * HEAD_DIM + ks * 32 + lg * 8);
                st[cf] = MFMA16(kf, qf[ks], st[cf]);
            }
        }
        // causal mask: provably only needed on the final tile
        if (kt == nkt - 1) {
            int qrow = q0 + l15;
#pragma unroll
            for (int cf = 0; cf < 4; cf++)
#pragma unroll
                for (int i = 0; i < 4; i++) {
                    int kv = kv0 + cf * 16 + lg * 4 + i;
                    if (kv > qrow) st[cf][i] = -1e30f;
                }
        }
        // per-q-row softmax: 16 in-lane values + 2-step shfl over lg
        float mx = -1e30f;
#pragma unroll
        for (int cf = 0; cf < 4; cf++)
#pragma unroll
            for (int i = 0; i < 4; i++) mx = fmaxf(mx, st[cf][i]);
        mx = fmaxf(mx, __shfl_xor(mx, 16, 64));
        mx = fmaxf(mx, __shfl_xor(mx, 32, 64));
        float mnew = fmaxf(mrun, mx);
        float alpha = exp2f(mrun - mnew);
        float ps = 0.f;
        bf16x4 pb[4];
#pragma unroll
        for (int cf = 0; cf < 4; cf++)
#pragma unroll
            for (int i = 0; i < 4; i++) {
                float p = exp2f(st[cf][i] - mnew);
                ps += p;
                pb[cf][i] = (bf16)p;
            }
        ps += __shfl_xor(ps, 16, 64);
        ps += __shfl_xor(ps, 32, 64);
        lrun = lrun * alpha + ps;
        mrun = mnew;
        // rescale O: O rows are q = lg*4+i -> fetch alpha from lane lg*4+i
        float av[4];
#pragma unroll
        for (int i = 0; i < 4; i++) av[i] = __shfl(alpha, lg * 4 + i, 64);
#pragma unroll
        for (int df = 0; df < 4; df++)
#pragma unroll
            for (int i = 0; i < 4; i++) oacc[df][i] *= av[i];
        // P -> LDS (XOR-swizzled rows), then read back as PV A-fragment
#pragma unroll
        for (int cf = 0; cf < 4; cf++) {
            int off = (l15 * 128 + cf * 32 + lg * 8) ^ swz;
            *(bf16x4*)(Pw + off) = pb[cf];
        }
        asm volatile("s_waitcnt lgkmcnt(0)" ::: "memory");
        __builtin_amdgcn_sched_barrier(0);
        bf16x8 pa[2];
#pragma unroll
        for (int ks = 0; ks < 2; ks++) {
            int off = (l15 * 128 + ks * 64 + lg * 16) ^ swz;
            pa[ks] = *(const bf16x8*)(Pw + off);
        }
#pragma unroll
        for (int ks = 0; ks < 2; ks++)
#pragma unroll
            for (int df = 0; df < 4; df++) {
                bf16x8 bv = *(const bf16x8*)(Vb + (size_t)(df * 16 + l15) * SEQ + kv0 + ks * 32 + lg * 8);
                oacc[df] = MFMA16(pa[ks], bv, oacc[df]);
            }
    }
    // final: divide row q by lrun[q]; stats live at lane q (q<16)
    float lrec = 1.0f / lrun;
    float lv[4];
#pragma unroll
    for (int i = 0; i < 4; i++) lv[i] = __shfl(lrec, lg * 4 + i, 64);
#pragma unroll
    for (int df = 0; df < 4; df++)
#pragma unroll
        for (int i = 0; i < 4; i++) {
            int qrow = q0 + lg * 4 + i;
            int d = df * 16 + l15;
            attn[((size_t)(b * SEQ + qrow)) * DMODEL + h * HEAD_DIM + d] = (bf16)(oacc[df][i] * lv[i]);
        }
}

// ---------------- launch ----------------

extern "C" void kernel_launch(void* const* d_in, const int* in_sizes, int n_in,
                              void* d_out, int out_size, void* d_ws, size_t ws_size,
                              hipStream_t stream) {
    const float* x  = (const float*)d_in[0];
    const float* wq = (const float*)d_in[1];
    const float* wk = (const float*)d_in[2];
    const float* wv = (const float*)d_in[3];
    const float* wo = (const float*)d_in[4];
    float* out = (float*)d_out;

    char* w = (char*)d_ws;
    bf16* xb  = (bf16*)(w);                        // 8 MB
    bf16* wqT = (bf16*)(w + (8ull  << 20));        // 2 MB
    bf16* wkT = (bf16*)(w + (10ull << 20));
    bf16* wvT = (bf16*)(w + (12ull << 20));
    bf16* woT = (bf16*)(w + (14ull << 20));
    bf16* Qh  = (bf16*)(w + (16ull << 20));        // 8 MB, [B][H][S][D]
    bf16* Kh  = (bf16*)(w + (24ull << 20));        // 8 MB, [B][H][S][D]
    bf16* Vt  = (bf16*)(w + (32ull << 20));        // 8 MB, [B][H][D][S]
    bf16* at  = (bf16*)(w + (40ull << 20));        // 8 MB  (total 48 MB)

    cvt_f32_bf16<<<(MROWS * DMODEL / 4 + 255) / 256, 256, 0, stream>>>(x, xb, MROWS * DMODEL / 4);
    cvt_trans<<<dim3(16, 16, 4), 256, 0, stream>>>(wq, wk, wv, wo, wqT, wkT, wvT, woT);
    gemm_qkv<<<dim3(DMODEL / BN, MROWS / BM, 3), 256, 0, stream>>>(xb, wqT, wkT, wvT, Qh, Kh, Vt);
    attn_kernel<<<dim3(2048, 1, 1), 128, 0, stream>>>(Qh, Kh, Vt, at);
    gemm_outp<<<dim3(DMODEL / BN, MROWS / BM), 256, 0, stream>>>(at, woT, out);
}